// Round 3
// baseline (1433.631 us; speedup 1.0000x reference)
//
#include <hip/hip_runtime.h>
#include <math.h>

#define BATCH 16
#define CIN 103
#define CCONV 256
#define NOUT 103
#define DOUT 16
#define RECSZ 8343
#define H1SZ 5562
#define H2SZ 12514

// ws float offsets
#define WS_P      0         // 16*256
#define WS_SQ     4096      // 16*256
#define WS_WSUM   8192      // 256*103*16 = 421888
#define WS_BB     430080    // 103*256 = 26368
#define WS_S      456448    // 16*103*16 = 26368
#define WS_FACTOR 482816    // 256
#define WS_F0T    483072    // 1648*16 = 26368   [k][b]
#define WS_F1T    509440    // 5562*16 = 88992   [k][b]
#define WS_F2T    598432    // 12514*16 = 200224 [k][b]
#define WS_RECT   798656    // 8343*16 = 133488  [n][b]
// total = 932144 floats = 3.6 MB

// ---------------- init: biases into transposed accumulators, bb = 1 ----------------
__global__ __launch_bounds__(256) void init_k(float* __restrict__ f1, const float* __restrict__ b1,
                                              float* __restrict__ f2, const float* __restrict__ b2,
                                              float* __restrict__ f3, const float* __restrict__ b3,
                                              float* __restrict__ bb) {
    int i = blockIdx.x * 256 + threadIdx.x;
    if (i < 16 * H1SZ) { f1[i] = b1[i >> 4]; return; }   // f1T[n*16+b] = b1[n]
    i -= 16 * H1SZ;
    if (i < 16 * H2SZ) { f2[i] = b2[i >> 4]; return; }
    i -= 16 * H2SZ;
    if (i < 16 * RECSZ) { f3[i] = b3[i >> 4]; return; }
    i -= 16 * RECSZ;
    if (i < 103 * 256) bb[i] = 1.0f;
}

// ---------------- conv (VALID 3x3) + relu + mean pool -> p[b][co] ----------------
__global__ __launch_bounds__(256) void conv_pool_k(const float* __restrict__ x,
                                                   const float* __restrict__ w,
                                                   const float* __restrict__ cb,
                                                   float* __restrict__ p) {
    int b = blockIdx.x >> 6;
    int cob = (blockIdx.x & 63) << 2;
    __shared__ float xs[CIN * 81];
    int t = threadIdx.x;
    for (int i = t; i < CIN * 81; i += 256) xs[i] = x[(size_t)b * CIN * 81 + i];
    __syncthreads();
    int wave = t >> 6, lane = t & 63;
    int co = cob + wave;
    co = __builtin_amdgcn_readfirstlane(co);
    int pos = lane < 49 ? lane : 0;
    int oh = pos / 7, ow = pos % 7;
    const float* wp = w + (size_t)co * CIN * 9;
    const float* xp = xs + oh * 9 + ow;
    float acc = 0.f;
    for (int ci = 0; ci < CIN; ++ci) {
#pragma unroll
        for (int kh = 0; kh < 3; ++kh)
#pragma unroll
            for (int kw = 0; kw < 3; ++kw)
                acc = fmaf(xp[ci * 81 + kh * 9 + kw], wp[ci * 9 + kh * 3 + kw], acc);
    }
    acc += cb[co];
    acc = fmaxf(acc, 0.f);
    if (lane >= 49) acc = 0.f;
#pragma unroll
    for (int off = 32; off; off >>= 1) acc += __shfl_down(acc, off);
    if (lane == 0) p[b * 256 + co] = acc * (1.0f / 49.0f);
}

// ---------------- squash p over c -> sq[b][c] ----------------
__global__ __launch_bounds__(256) void squash_p_k(const float* __restrict__ p, float* __restrict__ sq) {
    int b = blockIdx.x, c = threadIdx.x;
    float v = p[b * 256 + c];
    float ss = v * v;
#pragma unroll
    for (int off = 32; off; off >>= 1) ss += __shfl_down(ss, off);
    __shared__ float red[4];
    if ((c & 63) == 0) red[c >> 6] = ss;
    __syncthreads();
    float ms = red[0] + red[1] + red[2] + red[3];
    float mag = sqrtf(ms);
    sq[b * 256 + c] = v * mag / (1.f + ms);
}

// ---------------- Wsum[c][j][o] = sum_i W_caps[c][j][o][i] ----------------
__global__ __launch_bounds__(256) void wsum_k(const float* __restrict__ Wc, float* __restrict__ wsum) {
    int idx = blockIdx.x * 256 + threadIdx.x;
    const float4* p4 = (const float4*)(Wc + (size_t)idx * 32);
    float s = 0.f;
#pragma unroll
    for (int q = 0; q < 8; ++q) { float4 v = p4[q]; s += v.x + v.y + v.z + v.w; }
    wsum[idx] = s;
}

// ---------------- routing: softmax over c + s[b][j][o] ----------------
__global__ __launch_bounds__(256) void route_s_k(const float* __restrict__ sq,
                                                 const float* __restrict__ wsum,
                                                 const float* __restrict__ bb,
                                                 float* __restrict__ s_out) {
    int j = blockIdx.x;
    int t = threadIdx.x;
    __shared__ float sqst[4096];
    __shared__ float wls[4096];
    __shared__ float cc[256];
    __shared__ float red[8];
    float bv = bb[j * 256 + t];
    for (int i = t; i < 4096; i += 256) {
        sqst[i] = sq[((i & 15) << 8) + (i >> 4)];
        wls[i] = wsum[(size_t)(i >> 4) * (103 * 16) + j * 16 + (i & 15)];
    }
    int wave = t >> 6, lane = t & 63;
    float m = bv;
#pragma unroll
    for (int off = 32; off; off >>= 1) m = fmaxf(m, __shfl_down(m, off));
    if (lane == 0) red[wave] = m;
    __syncthreads();
    m = fmaxf(fmaxf(red[0], red[1]), fmaxf(red[2], red[3]));
    float e = expf(bv - m);
    float ssum = e;
#pragma unroll
    for (int off = 32; off; off >>= 1) ssum += __shfl_down(ssum, off);
    if (lane == 0) red[4 + wave] = ssum;
    __syncthreads();
    ssum = red[4] + red[5] + red[6] + red[7];
    cc[t] = e / ssum;
    __syncthreads();
    for (int i = t; i < 4096; i += 256) sqst[i] *= cc[i >> 4];
    __syncthreads();
    int b = t >> 4, o = t & 15;
    float acc = 0.f;
    for (int c = 0; c < 256; ++c)
        acc = fmaf(sqst[c * 16 + b], wls[c * 16 + o], acc);
    s_out[((size_t)b * 103 + j) * 16 + o] = acc;
}

// ---------------- squash factor over j: factor[b][o] ----------------
__global__ __launch_bounds__(256) void factor_k(const float* __restrict__ s, float* __restrict__ factor) {
    int t = threadIdx.x;
    int b = t >> 4, o = t & 15;
    const float* sp = s + (size_t)b * 103 * 16 + o;
    float ms = 0.f;
    int j = 0;
    for (; j + 8 <= 103; j += 8) {
        float v0 = sp[(j + 0) * 16], v1 = sp[(j + 1) * 16];
        float v2 = sp[(j + 2) * 16], v3 = sp[(j + 3) * 16];
        float v4 = sp[(j + 4) * 16], v5 = sp[(j + 5) * 16];
        float v6 = sp[(j + 6) * 16], v7 = sp[(j + 7) * 16];
        ms = fmaf(v0, v0, ms); ms = fmaf(v1, v1, ms);
        ms = fmaf(v2, v2, ms); ms = fmaf(v3, v3, ms);
        ms = fmaf(v4, v4, ms); ms = fmaf(v5, v5, ms);
        ms = fmaf(v6, v6, ms); ms = fmaf(v7, v7, ms);
    }
    for (; j < 103; ++j) { float v = sp[j * 16]; ms = fmaf(v, v, ms); }
    factor[t] = sqrtf(ms) / (1.f + ms);
}

// ---------------- agreement + bb update ----------------
__global__ __launch_bounds__(256) void route_upd_k(const float* __restrict__ sq,
                                                   const float* __restrict__ wsum,
                                                   const float* __restrict__ s,
                                                   const float* __restrict__ factor,
                                                   float* __restrict__ bb) {
    int j = blockIdx.x;
    int t = threadIdx.x;
    __shared__ float vs[256];
    {
        int b = t >> 4, o = t & 15;
        vs[t] = s[((size_t)b * 103 + j) * 16 + o] * factor[t];
    }
    __syncthreads();
    const float4* wp = (const float4*)(wsum + ((size_t)t * 103 + j) * 16);
    float4 w0 = wp[0], w1 = wp[1], w2 = wp[2], w3 = wp[3];
    float wv[16] = {w0.x, w0.y, w0.z, w0.w, w1.x, w1.y, w1.z, w1.w,
                    w2.x, w2.y, w2.z, w2.w, w3.x, w3.y, w3.z, w3.w};
    float acc = 0.f;
#pragma unroll
    for (int b = 0; b < 16; ++b) {
        float d = 0.f;
#pragma unroll
        for (int o = 0; o < 16; ++o) d = fmaf(wv[o], vs[b * 16 + o], d);
        acc = fmaf(sq[b * 256 + t], d, acc);
    }
    bb[j * 256 + t] += acc * (1.0f / 16.0f);
}

// ---------------- final v, ba output, f0T (transposed [k][b]) ----------------
__global__ __launch_bounds__(256) void final_v_k(const float* __restrict__ s,
                                                 const float* __restrict__ factor,
                                                 float* __restrict__ out_ba,
                                                 float* __restrict__ f0T) {
    int idx = blockIdx.x * 256 + threadIdx.x;
    if (idx >= 16 * 103) return;
    int b = idx / 103;
    int j = idx - b * 103;
    const float4* sp = (const float4*)(s + (size_t)idx * 16);
    float4 s0 = sp[0], s1 = sp[1], s2 = sp[2], s3 = sp[3];
    float sv[16] = {s0.x, s0.y, s0.z, s0.w, s1.x, s1.y, s1.z, s1.w,
                    s2.x, s2.y, s2.z, s2.w, s3.x, s3.y, s3.z, s3.w};
    float v[16];
    float nrm2 = 0.f;
#pragma unroll
    for (int o = 0; o < 16; ++o) {
        v[o] = sv[o] * factor[b * 16 + o];
        nrm2 = fmaf(v[o], v[o], nrm2);
    }
    float ba = sqrtf(nrm2);
    out_ba[idx] = ba;
    // f0T[k][b] with k = j*16+o
#pragma unroll
    for (int o = 0; o < 16; ++o)
        f0T[(size_t)(j * 16 + o) * 16 + b] = v[o] * ba;
}

// ---------------- FC: outT[n][b] += sum_k inT[k][b] * w[k][n]  (outT pre-set to bias) ----------------
// inT is [K][16] (64 B rows, wave-uniform address -> scalar-cache loads).
// Thread handles 2 adjacent columns; 4-row unroll. V2: float2 weight loads (even N);
// !V2: scalar pair (fc3, odd N). No LDS, no __syncthreads.
#define FMA16(VV, WA, WB)                                           \
    a0[0] = fmaf(VV.x, WA, a0[0]); a1[0] = fmaf(VV.x, WB, a1[0]);

template <bool V2>
__global__ __launch_bounds__(256) void fc_k(const float* __restrict__ inT,
                                            const float* __restrict__ w,
                                            float* __restrict__ outT,
                                            int K, int N, int kchunk) {
    const int tid = threadIdx.x;
    const int c0 = blockIdx.x * 512 + tid * 2;
    const int k0 = blockIdx.y * kchunk;
    int k1 = k0 + kchunk; if (k1 > K) k1 = K;
    const bool st0 = c0 < N;
    const bool st1 = (c0 + 1) < N;
    const int c = st0 ? c0 : 0;
    const int off1 = st1 ? 1 : 0;
    const size_t Ns = (size_t)N;
    const float* wp = w + (size_t)k0 * Ns + c;
    const float* ap = inT + (size_t)k0 * 16;

    float a0[16], a1[16];
#pragma unroll
    for (int b = 0; b < 16; ++b) { a0[b] = 0.f; a1[b] = 0.f; }

    int k = k0;
    for (; k + 4 <= k1; k += 4) {
        float wr0[4], wr1[4];
        if (V2) {
            float2 q0 = *(const float2*)(wp);
            float2 q1 = *(const float2*)(wp + Ns);
            float2 q2 = *(const float2*)(wp + 2 * Ns);
            float2 q3 = *(const float2*)(wp + 3 * Ns);
            wr0[0] = q0.x; wr1[0] = q0.y; wr0[1] = q1.x; wr1[1] = q1.y;
            wr0[2] = q2.x; wr1[2] = q2.y; wr0[3] = q3.x; wr1[3] = q3.y;
        } else {
            wr0[0] = wp[0];      wr1[0] = wp[off1];
            wr0[1] = wp[Ns];     wr1[1] = wp[Ns + off1];
            wr0[2] = wp[2 * Ns]; wr1[2] = wp[2 * Ns + off1];
            wr0[3] = wp[3 * Ns]; wr1[3] = wp[3 * Ns + off1];
        }
        wp += 4 * Ns;
#pragma unroll
        for (int r = 0; r < 4; ++r) {
            const float4 v0 = *(const float4*)(ap + r * 16);
            const float4 v1 = *(const float4*)(ap + r * 16 + 4);
            const float4 v2 = *(const float4*)(ap + r * 16 + 8);
            const float4 v3 = *(const float4*)(ap + r * 16 + 12);
            const float wa = wr0[r], wb = wr1[r];
            a0[0]  = fmaf(v0.x, wa, a0[0]);  a1[0]  = fmaf(v0.x, wb, a1[0]);
            a0[1]  = fmaf(v0.y, wa, a0[1]);  a1[1]  = fmaf(v0.y, wb, a1[1]);
            a0[2]  = fmaf(v0.z, wa, a0[2]);  a1[2]  = fmaf(v0.z, wb, a1[2]);
            a0[3]  = fmaf(v0.w, wa, a0[3]);  a1[3]  = fmaf(v0.w, wb, a1[3]);
            a0[4]  = fmaf(v1.x, wa, a0[4]);  a1[4]  = fmaf(v1.x, wb, a1[4]);
            a0[5]  = fmaf(v1.y, wa, a0[5]);  a1[5]  = fmaf(v1.y, wb, a1[5]);
            a0[6]  = fmaf(v1.z, wa, a0[6]);  a1[6]  = fmaf(v1.z, wb, a1[6]);
            a0[7]  = fmaf(v1.w, wa, a0[7]);  a1[7]  = fmaf(v1.w, wb, a1[7]);
            a0[8]  = fmaf(v2.x, wa, a0[8]);  a1[8]  = fmaf(v2.x, wb, a1[8]);
            a0[9]  = fmaf(v2.y, wa, a0[9]);  a1[9]  = fmaf(v2.y, wb, a1[9]);
            a0[10] = fmaf(v2.z, wa, a0[10]); a1[10] = fmaf(v2.z, wb, a1[10]);
            a0[11] = fmaf(v2.w, wa, a0[11]); a1[11] = fmaf(v2.w, wb, a1[11]);
            a0[12] = fmaf(v3.x, wa, a0[12]); a1[12] = fmaf(v3.x, wb, a1[12]);
            a0[13] = fmaf(v3.y, wa, a0[13]); a1[13] = fmaf(v3.y, wb, a1[13]);
            a0[14] = fmaf(v3.z, wa, a0[14]); a1[14] = fmaf(v3.z, wb, a1[14]);
            a0[15] = fmaf(v3.w, wa, a0[15]); a1[15] = fmaf(v3.w, wb, a1[15]);
        }
        ap += 64;
    }
    for (; k < k1; ++k) {
        float wa, wb;
        if (V2) { float2 q = *(const float2*)(wp); wa = q.x; wb = q.y; }
        else    { wa = wp[0]; wb = wp[off1]; }
        wp += Ns;
        const float4 v0 = *(const float4*)(ap);
        const float4 v1 = *(const float4*)(ap + 4);
        const float4 v2 = *(const float4*)(ap + 8);
        const float4 v3 = *(const float4*)(ap + 12);
        a0[0]  = fmaf(v0.x, wa, a0[0]);  a1[0]  = fmaf(v0.x, wb, a1[0]);
        a0[1]  = fmaf(v0.y, wa, a0[1]);  a1[1]  = fmaf(v0.y, wb, a1[1]);
        a0[2]  = fmaf(v0.z, wa, a0[2]);  a1[2]  = fmaf(v0.z, wb, a1[2]);
        a0[3]  = fmaf(v0.w, wa, a0[3]);  a1[3]  = fmaf(v0.w, wb, a1[3]);
        a0[4]  = fmaf(v1.x, wa, a0[4]);  a1[4]  = fmaf(v1.x, wb, a1[4]);
        a0[5]  = fmaf(v1.y, wa, a0[5]);  a1[5]  = fmaf(v1.y, wb, a1[5]);
        a0[6]  = fmaf(v1.z, wa, a0[6]);  a1[6]  = fmaf(v1.z, wb, a1[6]);
        a0[7]  = fmaf(v1.w, wa, a0[7]);  a1[7]  = fmaf(v1.w, wb, a1[7]);
        a0[8]  = fmaf(v2.x, wa, a0[8]);  a1[8]  = fmaf(v2.x, wb, a1[8]);
        a0[9]  = fmaf(v2.y, wa, a0[9]);  a1[9]  = fmaf(v2.y, wb, a1[9]);
        a0[10] = fmaf(v2.z, wa, a0[10]); a1[10] = fmaf(v2.z, wb, a1[10]);
        a0[11] = fmaf(v2.w, wa, a0[11]); a1[11] = fmaf(v2.w, wb, a1[11]);
        a0[12] = fmaf(v3.x, wa, a0[12]); a1[12] = fmaf(v3.x, wb, a1[12]);
        a0[13] = fmaf(v3.y, wa, a0[13]); a1[13] = fmaf(v3.y, wb, a1[13]);
        a0[14] = fmaf(v3.z, wa, a0[14]); a1[14] = fmaf(v3.w, wb, a1[14]);
        a0[15] = fmaf(v3.w, wa, a0[15]); a1[15] = fmaf(v3.w, wb, a1[15]);
        ap += 16;
    }
    if (st0) {
        float* op = outT + (size_t)c * 16;
#pragma unroll
        for (int b = 0; b < 16; ++b) atomicAdd(op + b, a0[b]);
    }
    if (st1) {
        float* op = outT + (size_t)(c + 1) * 16;
#pragma unroll
        for (int b = 0; b < 16; ++b) atomicAdd(op + b, a1[b]);
    }
}

// ---------------- transpose reconT[n][b] -> recon[b][n] ----------------
__global__ __launch_bounds__(256) void transp_k(const float* __restrict__ rT, float* __restrict__ out) {
    int n = blockIdx.x * 256 + threadIdx.x;
    int b = blockIdx.y;
    if (n < RECSZ) out[(size_t)b * RECSZ + n] = rT[(size_t)n * 16 + b];
}

extern "C" void kernel_launch(void* const* d_in, const int* in_sizes, int n_in,
                              void* d_out, int out_size, void* d_ws, size_t ws_size,
                              hipStream_t stream) {
    const float* x      = (const float*)d_in[0];
    const float* conv_w = (const float*)d_in[1];
    const float* conv_b = (const float*)d_in[2];
    const float* W_caps = (const float*)d_in[3];
    const float* fc1_w  = (const float*)d_in[4];
    const float* fc1_b  = (const float*)d_in[5];
    const float* fc2_w  = (const float*)d_in[6];
    const float* fc2_b  = (const float*)d_in[7];
    const float* fc3_w  = (const float*)d_in[8];
    const float* fc3_b  = (const float*)d_in[9];
    float* out = (float*)d_out;
    float* ws  = (float*)d_ws;

    float* p      = ws + WS_P;
    float* sq     = ws + WS_SQ;
    float* wsum   = ws + WS_WSUM;
    float* bb     = ws + WS_BB;
    float* s      = ws + WS_S;
    float* factor = ws + WS_FACTOR;
    float* f0T    = ws + WS_F0T;
    float* f1T    = ws + WS_F1T;
    float* f2T    = ws + WS_F2T;
    float* recT   = ws + WS_RECT;
    float* ba_out = out;            // 1648
    float* recon  = out + 1648;     // 133488

    init_k<<<1755, 256, 0, stream>>>(f1T, fc1_b, f2T, fc2_b, recT, fc3_b, bb);

    conv_pool_k<<<1024, 256, 0, stream>>>(x, conv_w, conv_b, p);
    squash_p_k<<<16, 256, 0, stream>>>(p, sq);
    wsum_k<<<1648, 256, 0, stream>>>(W_caps, wsum);

    for (int it = 0; it < 3; ++it) {
        route_s_k<<<103, 256, 0, stream>>>(sq, wsum, bb, s);
        factor_k<<<1, 256, 0, stream>>>(s, factor);
        if (it < 2)
            route_upd_k<<<103, 256, 0, stream>>>(sq, wsum, s, factor, bb);
    }
    final_v_k<<<7, 256, 0, stream>>>(s, factor, ba_out, f0T);

    // fc1: (16,1648)@(1648,5562), even N -> float2 path; 11x32 blocks, kchunk 52
    fc_k<true><<<dim3(11, 32), 256, 0, stream>>>(f0T, fc1_w, f1T, 1648, H1SZ, 52);
    // fc2: (16,5562)@(5562,12514), even N; 25x24 blocks, kchunk 232
    fc_k<true><<<dim3(25, 24), 256, 0, stream>>>(f1T, fc2_w, f2T, H1SZ, H2SZ, 232);
    // fc3: (16,12514)@(12514,8343), odd N -> scalar path; 17x24 blocks, kchunk 522
    fc_k<false><<<dim3(17, 24), 256, 0, stream>>>(f2T, fc3_w, recT, H2SZ, RECSZ, 522);

    transp_k<<<dim3(33, 16), 256, 0, stream>>>(recT, recon);
}